// Round 4
// baseline (68.757 us; speedup 1.0000x reference)
//
#include <hip/hip_runtime.h>

// FlatPoolIco: icosahedral 7-neighbor hex pooling with chart stitching.
// Input  x: (B=64, R=6, C=5, H=128, W=256) f32
// Output  : (B=64, R=6, C=5, 64, 128) f32
//
// out(h,w) = mean of 7 taps:
//   row 2h-1: cols {2w-1, 2w}          (padded row 0 when h==0)
//   row 2h  : cols {2w-1, 2w, 2w+1}
//   row 2h+1: cols {2w, 2w+1}
// Boundary stitches (only padded row 0 / col 0 reachable):
//   padded(0,pw): pw==0        -> x[b,0,0,0,0]
//                 pw in [1,128]  -> x[rot,      (c+4)%5, 127, 127+pw]
//                 pw in [129,256]-> x[(rot+1)%6,(c+4)%5, 256-pw, 255]
//   padded(ph,0): ph in [1,128]  -> x[(rot+5)%6,(c+4)%5, 127, 128-ph]
// Input vertex mask is redundant; output mask zeroes (63,0),(0,127)/slab.
//
// v3: one block per slab; each thread owns a 4-row x 8-col output strip and
//     rolls the 3-input-row window (B -> next T), cutting logical reads from
//     24 B/output to 18 B/output. Left edges via __shfl_up; lane 0 patches
//     from the stitched column. Nontemporal stores.

#define WW 256

typedef float vfloat4 __attribute__((ext_vector_type(4)));

__device__ __forceinline__ void load16(const float* p, float* d) {
    vfloat4 a = *(const vfloat4*)(p);
    vfloat4 b = *(const vfloat4*)(p + 4);
    vfloat4 c = *(const vfloat4*)(p + 8);
    vfloat4 e = *(const vfloat4*)(p + 12);
    d[0]=a.x;  d[1]=a.y;  d[2]=a.z;  d[3]=a.w;
    d[4]=b.x;  d[5]=b.y;  d[6]=b.z;  d[7]=b.w;
    d[8]=c.x;  d[9]=c.y;  d[10]=c.z; d[11]=c.w;
    d[12]=e.x; d[13]=e.y; d[14]=e.z; d[15]=e.w;
}

__global__ __launch_bounds__(256) void flat_pool_ico(const float* __restrict__ x,
                                                     float* __restrict__ out) {
    int slab = blockIdx.x;               // (b*6 + rot)*5 + c, 0..1919
    int lane = threadIdx.x & 15;         // 16 lanes per output row
    int hb   = (threadIdx.x >> 4) << 2;  // base output row: 0,4,...,60
    int c    = slab % 5;
    int rc   = slab / 5;                 // b*6 + rot
    int rot  = rc % 6;
    int b    = rc / 6;
    int cm   = lane << 4;                // input col base (16 per lane)

    const float* xs = x + ((long)slab << 15);            // own slab
    int cprev = (c + 4) % 5;
    const float* xn3 = x + ((long)((b * 6 + (rot + 5) % 6) * 5 + cprev) << 15) + 127 * WW;

    // T[j] = top row,  col cm+j-1  (padded(0,cm+j) when h==0)   j=0..15
    // M[j] = mid row,  col cm+j-1                                j=0..16
    // B[j] = bot row,  col cm+j                                  j=0..15
    float T[16], M[17], B[16];

    const float* rowm = xs + (hb << 9);                  // input row 2*hb
    load16(rowm + cm, &M[1]);
    {
        float ml = __shfl_up(M[16], 1);
        if (lane == 0) ml = xn3[127 - (hb << 1)];        // padded(2hb+1, 0)
        M[0] = ml;
    }
    load16(rowm + WW + cm, B);                           // input row 2*hb+1

    if (hb == 0) {
        // padded row 0 gather
        const float* xn1 = x + ((long)(rc * 5 + cprev) << 15) + 127 * WW + 127;
        const float* xn2 = x + ((long)((b * 6 + (rot + 1) % 6) * 5 + cprev) << 15) + 255;
        #pragma unroll
        for (int i = 0; i < 16; ++i) {
            int pw = cm + i;
            float v;
            if (pw == 0)        v = x[(long)b * 983040];   // corner -> flat idx 0
            else if (pw <= 128) v = xn1[pw];               // nbr chart row 127
            else                v = xn2[(256 - pw) << 8];  // nbr rot col 255
            T[i] = v;
        }
    } else {
        float tt[16];
        load16(rowm - WW + cm, tt);                      // input row 2*hb-1
        #pragma unroll
        for (int i = 0; i < 15; ++i) T[i + 1] = tt[i];
        float tl = __shfl_up(tt[15], 1);
        if (lane == 0) tl = xn3[128 - (hb << 1)];        // padded(2hb, 0)
        T[0] = tl;
    }

    const float inv7 = 1.0f / 7.0f;
    float* op = out + ((long)slab << 13) + (hb << 7) + (lane << 3);

    #pragma unroll
    for (int hh = 0; hh < 4; ++hh) {
        int h = hb + hh;
        float o[8];
        #pragma unroll
        for (int k = 0; k < 8; ++k) {
            float s = M[2*k] + M[2*k+1] + M[2*k+2]
                    + T[2*k] + T[2*k+1]
                    + B[2*k] + B[2*k+1];
            o[k] = s * inv7;
        }
        // output vertex mask: (63,0) and (0,127)
        if (h == 63 && lane == 0)  o[0] = 0.0f;
        if (h == 0  && lane == 15) o[7] = 0.0f;

        vfloat4 s0 = { o[0], o[1], o[2], o[3] };
        vfloat4 s1 = { o[4], o[5], o[6], o[7] };
        __builtin_nontemporal_store(s0, (vfloat4*)(op + (hh << 7)));
        __builtin_nontemporal_store(s1, (vfloat4*)(op + (hh << 7) + 4));

        if (hh < 3) {
            // slide: T <- B (shifted right by one col), B row becomes top row
            float tl = __shfl_up(B[15], 1);              // prev lane col cm-1
            if (lane == 0) tl = xn3[128 - ((h + 1) << 1)];   // padded(2h+2, 0)
            #pragma unroll
            for (int j = 15; j >= 1; --j) T[j] = B[j - 1];
            T[0] = tl;
            // M <- input row 2h+2 ; B <- input row 2h+3
            const float* rm = xs + ((h + 1) << 9);
            load16(rm + cm, &M[1]);
            float ml = __shfl_up(M[16], 1);
            if (lane == 0) ml = xn3[127 - ((h + 1) << 1)];   // padded(2h+3, 0)
            M[0] = ml;
            load16(rm + WW + cm, B);
        }
    }
}

extern "C" void kernel_launch(void* const* d_in, const int* in_sizes, int n_in,
                              void* d_out, int out_size, void* d_ws, size_t ws_size,
                              hipStream_t stream) {
    const float* x = (const float*)d_in[0];
    float* out = (float*)d_out;
    // one block per (b, rot, chart) slab: 64*6*5 = 1920 blocks
    flat_pool_ico<<<1920, 256, 0, stream>>>(x, out);
}

// Round 5
// 58.744 us; speedup vs baseline: 1.1704x; 1.1704x over previous
//
#include <hip/hip_runtime.h>

// FlatPoolIco: icosahedral 7-neighbor hex pooling with chart stitching.
// Input  x: (B=64, R=6, C=5, H=128, W=256) f32
// Output  : (B=64, R=6, C=5, 64, 128) f32
//
// out(h,w) = mean of 7 taps:
//   row 2h-1: cols {2w-1, 2w}          (padded row 0 when h==0)
//   row 2h  : cols {2w-1, 2w, 2w+1}
//   row 2h+1: cols {2w, 2w+1}
// Boundary stitches (only padded row 0 / col 0 reachable):
//   padded(0,pw): pw==0        -> x[b,0,0,0,0]
//                 pw in [1,128]  -> x[rot,      (c+4)%5, 127, 127+pw]
//                 pw in [129,256]-> x[(rot+1)%6,(c+4)%5, 256-pw, 255]
//   padded(ph,0): ph in [1,128]  -> x[(rot+5)%6,(c+4)%5, 127, 128-ph]
// Input vertex mask is redundant; output mask zeroes (63,0),(0,127)/slab.
//
// v2 (reverted from v3): 8 outputs/thread, 16 lanes per output row, left
// edge via __shfl_up, nontemporal stores. v3's rolling-strip regressed:
// its byte "savings" were already L1-absorbed in v2 (block = 16 contiguous
// output rows), and the serialized window rotation killed latency hiding.

#define WW 256

typedef float vfloat4 __attribute__((ext_vector_type(4)));

__global__ __launch_bounds__(256) void flat_pool_ico(const float* __restrict__ x,
                                                     float* __restrict__ out) {
    int t = blockIdx.x * 256 + threadIdx.x;
    int lane = t & 15;           // 16 threads per output row
    int rowid = t >> 4;
    int h = rowid & 63;
    int tmp = rowid >> 6;
    int c = tmp % 5; tmp /= 5;
    int rot = tmp % 6;
    int b = tmp / 6;
    int w0 = lane << 3;          // output col start: 0..120
    int cm = w0 << 1;            // input col base:   16*lane

    long slab = (long)((b * 6 + rot) * 5 + c);
    const float* xs   = x + (slab << 15);     // own slab (32768 floats)
    const float* rowm = xs + (h << 9);        // input row 2h
    const float* rowb = rowm + WW;            // input row 2h+1

    // M[j] = row 2h   col cm+j-1   (j=0..16)
    // T[j] = row 2h-1 col cm+j-1,  or padded(0, cm+j) when h==0  (j=0..15)
    // B[j] = row 2h+1 col cm+j     (j=0..15)
    float M[17], T[16], B[16];

    {
        vfloat4 a0 = *(const vfloat4*)(rowm + cm);
        vfloat4 a1 = *(const vfloat4*)(rowm + cm + 4);
        vfloat4 a2 = *(const vfloat4*)(rowm + cm + 8);
        vfloat4 a3 = *(const vfloat4*)(rowm + cm + 12);
        M[1]=a0.x;  M[2]=a0.y;  M[3]=a0.z;  M[4]=a0.w;
        M[5]=a1.x;  M[6]=a1.y;  M[7]=a1.z;  M[8]=a1.w;
        M[9]=a2.x;  M[10]=a2.y; M[11]=a2.z; M[12]=a2.w;
        M[13]=a3.x; M[14]=a3.y; M[15]=a3.z; M[16]=a3.w;
        vfloat4 c0 = *(const vfloat4*)(rowb + cm);
        vfloat4 c1 = *(const vfloat4*)(rowb + cm + 4);
        vfloat4 c2 = *(const vfloat4*)(rowb + cm + 8);
        vfloat4 c3 = *(const vfloat4*)(rowb + cm + 12);
        B[0]=c0.x;  B[1]=c0.y;  B[2]=c0.z;  B[3]=c0.w;
        B[4]=c1.x;  B[5]=c1.y;  B[6]=c1.z;  B[7]=c1.w;
        B[8]=c2.x;  B[9]=c2.y;  B[10]=c2.z; B[11]=c2.w;
        B[12]=c3.x; B[13]=c3.y; B[14]=c3.z; B[15]=c3.w;
    }

    int cprev = (c + 4) % 5;
    const float* xn3 = x + ((long)((b * 6 + (rot + 5) % 6) * 5 + cprev) << 15) + 127 * WW;

    // left edge of mid row: col cm-1 (prev lane's M[16]); lane 0 stitched
    {
        float midL = __shfl_up(M[16], 1);
        if (lane == 0) midL = xn3[127 - (h << 1)];   // padded(1+2h, 0)
        M[0] = midL;
    }

    if (h == 0) {
        // padded row 0: T[i] = padded(0, cm+i)
        const float* xn1 = x + ((long)((b * 6 + rot) * 5 + cprev) << 15) + 127 * WW + 127;
        const float* xn2 = x + ((long)((b * 6 + (rot + 1) % 6) * 5 + cprev) << 15) + 255;
        #pragma unroll
        for (int i = 0; i < 16; ++i) {
            int pw = cm + i;
            float v;
            if (pw == 0)        v = x[(long)b * 983040];   // corner -> flat idx 0
            else if (pw <= 128) v = xn1[pw];               // nbr chart row 127
            else                v = xn2[(256 - pw) << 8];  // nbr rot col 255
            T[i] = v;
        }
    } else {
        const float* rowt = rowm - WW;        // input row 2h-1
        vfloat4 t0 = *(const vfloat4*)(rowt + cm);
        vfloat4 t1 = *(const vfloat4*)(rowt + cm + 4);
        vfloat4 t2 = *(const vfloat4*)(rowt + cm + 8);
        vfloat4 t3 = *(const vfloat4*)(rowt + cm + 12);
        T[1]=t0.x;  T[2]=t0.y;  T[3]=t0.z;  T[4]=t0.w;
        T[5]=t1.x;  T[6]=t1.y;  T[7]=t1.z;  T[8]=t1.w;
        T[9]=t2.x;  T[10]=t2.y; T[11]=t2.z; T[12]=t2.w;
        T[13]=t3.x; T[14]=t3.y; T[15]=t3.z;
        float topL = __shfl_up(t3.w, 1);      // prev lane's col cm-1
        if (lane == 0) topL = xn3[128 - (h << 1)];   // padded(2h, 0)
        T[0] = topL;
    }

    const float inv7 = 1.0f / 7.0f;
    float o[8];
    #pragma unroll
    for (int k = 0; k < 8; ++k) {
        float s = M[2*k] + M[2*k+1] + M[2*k+2]
                + T[2*k] + T[2*k+1]
                + B[2*k] + B[2*k+1];
        o[k] = s * inv7;
    }

    // output vertex mask: (63,0) and (0,127)
    if (h == 63 && lane == 0)  o[0] = 0.0f;
    if (h == 0  && lane == 15) o[7] = 0.0f;

    float* op = out + (slab << 13) + (h << 7) + w0;
    vfloat4 s0 = { o[0], o[1], o[2], o[3] };
    vfloat4 s1 = { o[4], o[5], o[6], o[7] };
    __builtin_nontemporal_store(s0, (vfloat4*)op);
    __builtin_nontemporal_store(s1, (vfloat4*)(op + 4));
}

extern "C" void kernel_launch(void* const* d_in, const int* in_sizes, int n_in,
                              void* d_out, int out_size, void* d_ws, size_t ws_size,
                              hipStream_t stream) {
    const float* x = (const float*)d_in[0];
    float* out = (float*)d_out;
    // threads = 64*6*5*64*16 = 1,966,080 ; 256/block -> 7680 blocks
    flat_pool_ico<<<7680, 256, 0, stream>>>(x, out);
}